// Round 6
// baseline (1229.728 us; speedup 1.0000x reference)
//
#include <hip/hip_runtime.h>
#include <hip/hip_fp16.h>
#include <cmath>

#define NN 20000
#define EE 500000
#define GG 64
#define TS 4096
#define EPS 1e-5f

__device__ __forceinline__ float softplus_ref(float x) {
    return fmaxf(x, 0.f) + log1pf(__expf(-fabsf(x)));
}
__device__ __forceinline__ float softplus_fast(float x) {
    return fmaxf(x, 0.f) + __logf(1.0f + __expf(-fabsf(x)));
}
__device__ __forceinline__ float sigmoid_fast(float x) {
    return __builtin_amdgcn_rcpf(1.0f + __expf(-x));
}

// gaussian table: g[s][k] = exp(coeff*(d_s - o_k)^2)
__global__ void k_gtab(float* __restrict__ g) {
    int i = blockIdx.x * 256 + threadIdx.x;
    if (i >= TS * 100) return;
    int s = i / 100, k = i - 100 * s;
    float d = s * (6.0f / 4095.0f);
    float o = k * (6.0f / 99.0f);
    float step = 6.0f / 99.0f;
    float coeff = -0.5f / (step * step);
    float df = d - o;
    g[i] = __expf(coeff * df * df);
}

// Paired channel layout: Tp[l][s][t] = half2(T[c=t], T[c=t+64]), t in [0,64)
__global__ void k_build_T(const float* __restrict__ g, const float* __restrict__ convW,
                          const float* __restrict__ convB, __half2* __restrict__ Tp) {
    int t = threadIdx.x;            // 64
    int s = blockIdx.x;             // TS
    int l = blockIdx.y;             // 6
    const float* gr = g + (size_t)s * 100;
    const float* w = convW + ((size_t)l * 228 + 128) * 128;
    float a0 = convB[l * 128 + t];
    float a1 = convB[l * 128 + t + 64];
#pragma unroll 4
    for (int k = 0; k < 100; k++) {
        float gv = gr[k];
        a0 += gv * w[k * 128 + t];
        a1 += gv * w[k * 128 + t + 64];
    }
    Tp[((size_t)l * TS + s) * 64 + t] = __floats2half2_rn(a0, a1);
}

// Tq4[l][j][c] = uint4{ (Tj[c],Tj[c+32]), (Tj[c+64],Tj[c+96]),
//                       (Tj1[c],Tj1[c+32]), (Tj1[c+64],Tj1[c+96]) }, c in [0,32)
__global__ void k_build_Tq4(const __half2* __restrict__ Tp, uint4* __restrict__ Tq4) {
    int c = threadIdx.x & 31;
    int j = blockIdx.x * 8 + (threadIdx.x >> 5);   // TS/8 blocks
    int l = blockIdx.y;
    int j1 = min(j + 1, TS - 1);
    __half2 p0a = Tp[((size_t)l * TS + j) * 64 + c];        // (Tj[c], Tj[c+64])
    __half2 p0b = Tp[((size_t)l * TS + j) * 64 + c + 32];   // (Tj[c+32], Tj[c+96])
    __half2 p1a = Tp[((size_t)l * TS + j1) * 64 + c];
    __half2 p1b = Tp[((size_t)l * TS + j1) * 64 + c + 32];
    __half2 A, B, C, D;
    A.x = p0a.x; A.y = p0b.x;
    B.x = p0a.y; B.y = p0b.y;
    C.x = p1a.x; C.y = p1b.x;
    D.x = p1a.y; D.y = p1b.y;
    uint4 out;
    out.x = *(unsigned*)&A; out.y = *(unsigned*)&B;
    out.z = *(unsigned*)&C; out.w = *(unsigned*)&D;
    Tq4[((size_t)l * TS + j) * 32 + c] = out;
}

// Wp[l][k][lane] = (W1[k,lane], W1[k,lane+64], W2[k,lane], W2[k,lane+64])
__global__ void k_prepW(const float* __restrict__ convW, float4* __restrict__ Wp) {
    int lane = threadIdx.x;  // 64
    int k = blockIdx.x;      // 64
    int l = blockIdx.y;      // 6
    const float* W1 = convW + ((size_t)l * 228 + k) * 128;
    const float* W2 = convW + ((size_t)l * 228 + 64 + k) * 128;
    Wp[((size_t)l * 64 + k) * 64 + lane] =
        make_float4(W1[lane], W1[lane + 64], W2[lane], W2[lane + 64]);
}

__global__ void k_embed(const int* __restrict__ an, const float* __restrict__ emb,
                        const float* __restrict__ W, const float* __restrict__ b,
                        float* __restrict__ x) {
    int c = threadIdx.x & 63, nl = threadIdx.x >> 6;
    int n = blockIdx.x * 4 + nl;
    if (n >= NN) return;
    const float* e = emb + (size_t)an[n] * 92;
    float acc = b[c];
#pragma unroll 4
    for (int k = 0; k < 92; k++) acc += e[k] * W[k * 64 + c];
    x[(size_t)n * 64 + c] = acc;
}

__global__ void k_hist(const int* __restrict__ dst, int* __restrict__ counts) {
    int e = blockIdx.x * 256 + threadIdx.x;
    if (e < EE) atomicAdd(&counts[dst[e]], 1);
}

__global__ void k_scan(const int* __restrict__ counts, int* __restrict__ rp) {
    __shared__ int buf[1024];
    __shared__ int carry;
    int tid = threadIdx.x;
    if (tid == 0) { carry = 0; rp[0] = 0; }
    __syncthreads();
    for (int base = 0; base < NN; base += 1024) {
        int i = base + tid;
        int val = (i < NN) ? counts[i] : 0;
        buf[tid] = val;
        __syncthreads();
        for (int off = 1; off < 1024; off <<= 1) {
            int t = (tid >= off) ? buf[tid - off] : 0;
            __syncthreads();
            buf[tid] += t;
            __syncthreads();
        }
        if (i < NN) rp[i + 1] = carry + buf[tid];
        __syncthreads();
        if (tid == 0) carry += buf[1023];
        __syncthreads();
    }
}

__global__ void k_scatter(const int* __restrict__ dst, const int* __restrict__ rp,
                          int* __restrict__ cursor, int* __restrict__ perm) {
    int e = blockIdx.x * 256 + threadIdx.x;
    if (e < EE) {
        int d = dst[e];
        int p = atomicAdd(&cursor[d], 1);
        perm[rp[d] + p] = e;
    }
}

// packed edge record in perm order: (src<<17) | (j<<5) | f5
__global__ void k_edges(const int* __restrict__ perm, const int* __restrict__ src,
                        const float* __restrict__ dist, unsigned* __restrict__ ej) {
    int idx = blockIdx.x * 256 + threadIdx.x;
    if (idx >= EE) return;
    int e = perm[idx];
    float t = dist[e] * (4095.0f / 6.0f);
    int j = (int)t;
    if (j > TS - 2) j = TS - 2;
    float f = t - (float)j;
    f = fminf(fmaxf(f, 0.0f), 1.0f);
    unsigned f5 = (unsigned)(f * 32.0f);
    if (f5 > 31u) f5 = 31u;
    ej[idx] = ((unsigned)src[e] << 17) | ((unsigned)j << 5) | f5;
}

// u,v: 4 nodes per wave; store in 4-ch/lane layout:
// up4[n*32+c] = uint2{ h2(u_c,u_{c+32}), h2(u_{c+64},u_{c+96}) }
__global__ void __launch_bounds__(256) k_uv(const float* __restrict__ x,
                                            const float4* __restrict__ Wp,
                                            uint2* __restrict__ up4, uint2* __restrict__ vp4) {
    int lane = threadIdx.x & 63;
    int wv = __builtin_amdgcn_readfirstlane(threadIdx.x >> 6);
    int n0 = (blockIdx.x * 4 + wv) * 4;
    float xa = x[(size_t)(n0 + 0) * 64 + lane];
    float xb = x[(size_t)(n0 + 1) * 64 + lane];
    float xc = x[(size_t)(n0 + 2) * 64 + lane];
    float xd = x[(size_t)(n0 + 3) * 64 + lane];
    float2 ua = {0, 0}, ub = {0, 0}, uc = {0, 0}, ud = {0, 0};
    float2 va = {0, 0}, vb = {0, 0}, vc = {0, 0}, vd = {0, 0};
#pragma unroll 8
    for (int k = 0; k < 64; k++) {
        float4 w = Wp[k * 64 + lane];
        float ka = __uint_as_float(__builtin_amdgcn_readlane(__float_as_uint(xa), k));
        float kb = __uint_as_float(__builtin_amdgcn_readlane(__float_as_uint(xb), k));
        float kc = __uint_as_float(__builtin_amdgcn_readlane(__float_as_uint(xc), k));
        float kd = __uint_as_float(__builtin_amdgcn_readlane(__float_as_uint(xd), k));
        ua.x += ka * w.x; ua.y += ka * w.y; va.x += ka * w.z; va.y += ka * w.w;
        ub.x += kb * w.x; ub.y += kb * w.y; vb.x += kb * w.z; vb.y += kb * w.w;
        uc.x += kc * w.x; uc.y += kc * w.y; vc.x += kc * w.z; vc.y += kc * w.w;
        ud.x += kd * w.x; ud.y += kd * w.y; vd.x += kd * w.z; vd.y += kd * w.w;
    }
    int c = lane & 31;
    int sl = c + 32;   // partner lane holding ch c+32 / c+96
    bool lo = lane < 32;
#define STORE4(arr, n, P)                                                   \
    {                                                                       \
        float o0 = __shfl(P.x, sl, 64);                                     \
        float o1 = __shfl(P.y, sl, 64);                                     \
        if (lo) {                                                           \
            uint2 r;                                                        \
            __half2 h0 = __floats2half2_rn(P.x, o0);                        \
            __half2 h1 = __floats2half2_rn(P.y, o1);                        \
            r.x = *(unsigned*)&h0; r.y = *(unsigned*)&h1;                   \
            arr[(size_t)(n)*32 + c] = r;                                    \
        }                                                                   \
    }
    STORE4(up4, n0 + 0, ua) STORE4(up4, n0 + 1, ub)
    STORE4(up4, n0 + 2, uc) STORE4(up4, n0 + 3, ud)
    STORE4(vp4, n0 + 0, va) STORE4(vp4, n0 + 1, vb)
    STORE4(vp4, n0 + 2, vc) STORE4(vp4, n0 + 3, vd)
#undef STORE4
}

__device__ __forceinline__ void pair_z(uint2 vraw, uint4 traw, float f,
                                       float2 uA, float2 uB,
                                       float& z0, float& z1, float& z2, float& z3) {
    float2 vA = __half22float2(*(const __half2*)&vraw.x);   // v[c], v[c+32]
    float2 vB = __half22float2(*(const __half2*)&vraw.y);   // v[c+64], v[c+96]
    float2 t0A = __half22float2(*(const __half2*)&traw.x);
    float2 t0B = __half22float2(*(const __half2*)&traw.y);
    float2 t1A = __half22float2(*(const __half2*)&traw.z);
    float2 t1B = __half22float2(*(const __half2*)&traw.w);
    z0 = uA.x + vA.x + t0A.x + (t1A.x - t0A.x) * f;
    z1 = uA.y + vA.y + t0A.y + (t1A.y - t0A.y) * f;
    z2 = uB.x + vB.x + t0B.x + (t1B.x - t0B.x) * f;
    z3 = uB.y + vB.y + t0B.y + (t1B.y - t0B.y) * f;
}

// pass A: BN stats; 2 edges/wave (32 lanes each), scalar edge records, 4-pair unroll
__global__ void __launch_bounds__(256) k_stats(
    const uint2* __restrict__ up4, const uint2* __restrict__ vp4,
    const uint4* __restrict__ Tq4, const unsigned* __restrict__ ej,
    const int* __restrict__ rp, float* __restrict__ sums) {
    int tid = threadIdx.x;
    int c = tid & 31;
    int half = (tid >> 5) & 1;
    int wv = tid >> 6;
    float s0 = 0, s1 = 0, s2 = 0, s3 = 0, q0 = 0, q1 = 0, q2 = 0, q3 = 0;
    for (int i = blockIdx.x * 4 + wv; i < NN; i += gridDim.x * 4) {
        uint2 uraw = up4[(size_t)i * 32 + c];
        float2 uA = __half22float2(*(const __half2*)&uraw.x);
        float2 uB = __half22float2(*(const __half2*)&uraw.y);
        int rs = __builtin_amdgcn_readfirstlane(rp[i]);
        int re = __builtin_amdgcn_readfirstlane(rp[i + 1]);
        int idx = rs;
        for (; idx + 8 <= re; idx += 8) {
            unsigned er[8];
#pragma unroll
            for (int t = 0; t < 8; t++) er[t] = ej[idx + t];
            uint2 vr[4]; uint4 tr[4]; float ff[4];
#pragma unroll
            for (int p = 0; p < 4; p++) {
                unsigned esel = half ? er[2 * p + 1] : er[2 * p];
                ff[p] = ((float)(esel & 31u) + 0.5f) * (1.0f / 32.0f);
                vr[p] = vp4[(size_t)(esel >> 17) * 32 + c];
                tr[p] = Tq4[(size_t)((esel >> 5) & 0xFFFu) * 32 + c];
            }
#pragma unroll
            for (int p = 0; p < 4; p++) {
                float z0, z1, z2, z3;
                pair_z(vr[p], tr[p], ff[p], uA, uB, z0, z1, z2, z3);
                s0 += z0; q0 += z0 * z0; s1 += z1; q1 += z1 * z1;
                s2 += z2; q2 += z2 * z2; s3 += z3; q3 += z3 * z3;
            }
        }
        for (; idx + 2 <= re; idx += 2) {
            unsigned e0 = ej[idx], e1 = ej[idx + 1];
            unsigned esel = half ? e1 : e0;
            float f = ((float)(esel & 31u) + 0.5f) * (1.0f / 32.0f);
            uint2 vraw = vp4[(size_t)(esel >> 17) * 32 + c];
            uint4 traw = Tq4[(size_t)((esel >> 5) & 0xFFFu) * 32 + c];
            float z0, z1, z2, z3;
            pair_z(vraw, traw, f, uA, uB, z0, z1, z2, z3);
            s0 += z0; q0 += z0 * z0; s1 += z1; q1 += z1 * z1;
            s2 += z2; q2 += z2 * z2; s3 += z3; q3 += z3 * z3;
        }
        if (idx < re) {
            unsigned e0 = ej[idx];
            float f = ((float)(e0 & 31u) + 0.5f) * (1.0f / 32.0f);
            uint2 vraw = vp4[(size_t)(e0 >> 17) * 32 + c];
            uint4 traw = Tq4[(size_t)((e0 >> 5) & 0xFFFu) * 32 + c];
            float z0, z1, z2, z3;
            pair_z(vraw, traw, f, uA, uB, z0, z1, z2, z3);
            if (half == 0) {
                s0 += z0; q0 += z0 * z0; s1 += z1; q1 += z1 * z1;
                s2 += z2; q2 += z2 * z2; s3 += z3; q3 += z3 * z3;
            }
        }
    }
    // combine halves (same channels, different edges)
    s0 += __shfl_xor(s0, 32, 64); s1 += __shfl_xor(s1, 32, 64);
    s2 += __shfl_xor(s2, 32, 64); s3 += __shfl_xor(s3, 32, 64);
    q0 += __shfl_xor(q0, 32, 64); q1 += __shfl_xor(q1, 32, 64);
    q2 += __shfl_xor(q2, 32, 64); q3 += __shfl_xor(q3, 32, 64);
    __shared__ float red[4][32][8];
    if (half == 0) {
        red[wv][c][0] = s0; red[wv][c][1] = s1;
        red[wv][c][2] = s2; red[wv][c][3] = s3;
        red[wv][c][4] = q0; red[wv][c][5] = q1;
        red[wv][c][6] = q2; red[wv][c][7] = q3;
    }
    __syncthreads();
    if (tid < 32) {
        float a[8];
#pragma unroll
        for (int k = 0; k < 8; k++)
            a[k] = red[0][tid][k] + red[1][tid][k] + red[2][tid][k] + red[3][tid][k];
        atomicAdd(&sums[tid], a[0]);
        atomicAdd(&sums[tid + 32], a[1]);
        atomicAdd(&sums[tid + 64], a[2]);
        atomicAdd(&sums[tid + 96], a[3]);
        atomicAdd(&sums[128 + tid], a[4]);
        atomicAdd(&sums[128 + tid + 32], a[5]);
        atomicAdd(&sums[128 + tid + 64], a[6]);
        atomicAdd(&sums[128 + tid + 96], a[7]);
    }
}

// pass B: 2 edges/wave; inline BN fold; LN+residual+softplus epilogue in shuffles
__global__ void __launch_bounds__(256) k_agg(
    const uint2* __restrict__ up4, const uint2* __restrict__ vp4,
    const uint4* __restrict__ Tq4, const unsigned* __restrict__ ej,
    const int* __restrict__ rp, const float* __restrict__ sums,
    const float* __restrict__ bng, const float* __restrict__ bnb,
    const float* __restrict__ lng, const float* __restrict__ lnb,
    int l, const float* __restrict__ xin, float* __restrict__ xout) {
    int tid = threadIdx.x;
    int c = tid & 31;
    int half = (tid >> 5) & 1;
    int wv = tid >> 6;
    int i = blockIdx.x * 4 + wv;
    float A[4], B[4];
#pragma unroll
    for (int t = 0; t < 4; t++) {
        int ch = c + 32 * t;
        float mu = sums[ch] * (1.0f / EE);
        float var = sums[128 + ch] * (1.0f / EE) - mu * mu;
        float Av = rsqrtf(var + EPS) * bng[l * 128 + ch];
        A[t] = Av; B[t] = bnb[l * 128 + ch] - mu * Av;
    }
    uint2 uraw = up4[(size_t)i * 32 + c];
    float2 uA = __half22float2(*(const __half2*)&uraw.x);
    float2 uB = __half22float2(*(const __half2*)&uraw.y);
    float acc0 = 0.f, acc1 = 0.f;
    int rs = __builtin_amdgcn_readfirstlane(rp[i]);
    int re = __builtin_amdgcn_readfirstlane(rp[i + 1]);
    int idx = rs;
    for (; idx + 8 <= re; idx += 8) {
        unsigned er[8];
#pragma unroll
        for (int t = 0; t < 8; t++) er[t] = ej[idx + t];
        uint2 vr[4]; uint4 tr[4]; float ff[4];
#pragma unroll
        for (int p = 0; p < 4; p++) {
            unsigned esel = half ? er[2 * p + 1] : er[2 * p];
            ff[p] = ((float)(esel & 31u) + 0.5f) * (1.0f / 32.0f);
            vr[p] = vp4[(size_t)(esel >> 17) * 32 + c];
            tr[p] = Tq4[(size_t)((esel >> 5) & 0xFFFu) * 32 + c];
        }
#pragma unroll
        for (int p = 0; p < 4; p++) {
            float z0, z1, z2, z3;
            pair_z(vr[p], tr[p], ff[p], uA, uB, z0, z1, z2, z3);
            acc0 += sigmoid_fast(z0 * A[0] + B[0]) * softplus_fast(z2 * A[2] + B[2]);
            acc1 += sigmoid_fast(z1 * A[1] + B[1]) * softplus_fast(z3 * A[3] + B[3]);
        }
    }
    for (; idx + 2 <= re; idx += 2) {
        unsigned e0 = ej[idx], e1 = ej[idx + 1];
        unsigned esel = half ? e1 : e0;
        float f = ((float)(esel & 31u) + 0.5f) * (1.0f / 32.0f);
        uint2 vraw = vp4[(size_t)(esel >> 17) * 32 + c];
        uint4 traw = Tq4[(size_t)((esel >> 5) & 0xFFFu) * 32 + c];
        float z0, z1, z2, z3;
        pair_z(vraw, traw, f, uA, uB, z0, z1, z2, z3);
        acc0 += sigmoid_fast(z0 * A[0] + B[0]) * softplus_fast(z2 * A[2] + B[2]);
        acc1 += sigmoid_fast(z1 * A[1] + B[1]) * softplus_fast(z3 * A[3] + B[3]);
    }
    if (idx < re) {
        unsigned e0 = ej[idx];
        float f = ((float)(e0 & 31u) + 0.5f) * (1.0f / 32.0f);
        uint2 vraw = vp4[(size_t)(e0 >> 17) * 32 + c];
        uint4 traw = Tq4[(size_t)((e0 >> 5) & 0xFFFu) * 32 + c];
        float z0, z1, z2, z3;
        pair_z(vraw, traw, f, uA, uB, z0, z1, z2, z3);
        if (half == 0) {
            acc0 += sigmoid_fast(z0 * A[0] + B[0]) * softplus_fast(z2 * A[2] + B[2]);
            acc1 += sigmoid_fast(z1 * A[1] + B[1]) * softplus_fast(z3 * A[3] + B[3]);
        }
    }
    // combine halves: all lanes now hold full per-channel sums (ch c and c+32)
    acc0 += __shfl_xor(acc0, 32, 64);
    acc1 += __shfl_xor(acc1, 32, 64);
    float s = acc0 + acc1;
#pragma unroll
    for (int off = 16; off; off >>= 1) s += __shfl_xor(s, off, 64);
    float mean = s * (1.0f / 64.0f);
    float e0v = acc0 - mean, e1v = acc1 - mean;
    float vv = e0v * e0v + e1v * e1v;
#pragma unroll
    for (int off = 16; off; off >>= 1) vv += __shfl_xor(vv, off, 64);
    float rstd = rsqrtf(vv * (1.0f / 64.0f) + EPS);
    float h0 = e0v * rstd * lng[l * 64 + c] + lnb[l * 64 + c];
    float h1 = e1v * rstd * lng[l * 64 + c + 32] + lnb[l * 64 + c + 32];
    int lane = tid & 63;
    float hv = (lane < 32) ? h0 : h1;   // lane>=32 holds ch c+32 correctly
    float xr = xin[(size_t)i * 64 + lane];
    xout[(size_t)i * 64 + lane] = softplus_ref(hv + xr);
}

// batch sorted -> graph row pointers by binary search
__global__ void k_gp(const int* __restrict__ batch, int* __restrict__ gp) {
    int g = threadIdx.x;
    if (g > GG) return;
    int lo = 0, hi = NN;
    while (lo < hi) {
        int mid = (lo + hi) >> 1;
        if (batch[mid] < g) lo = mid + 1; else hi = mid;
    }
    gp[g] = lo;
}

// atomic-free segmented mean-pool
__global__ void k_pool2(const float* __restrict__ x, const int* __restrict__ gp,
                        float* __restrict__ mols) {
    int g = blockIdx.x;
    int lane = threadIdx.x & 63, slot = threadIdx.x >> 6;
    int s0 = gp[g], s1 = gp[g + 1];
    float acc = 0.f;
    for (int n = s0 + slot; n < s1; n += 4) acc += x[(size_t)n * 64 + lane];
    __shared__ float red[4][64];
    red[slot][lane] = acc;
    __syncthreads();
    if (slot == 0) {
        float a = red[0][lane] + red[1][lane] + red[2][lane] + red[3][lane];
        float cc = fmaxf((float)(s1 - s0), 1.0f);
        mols[g * 64 + lane] = a / cc;
    }
}

__global__ void k_mlp(const float* __restrict__ mols,
                      const float* __restrict__ fc1W, const float* __restrict__ fc1b,
                      const float* __restrict__ fcsW, const float* __restrict__ fcsb,
                      const float* __restrict__ outW, const float* __restrict__ outb,
                      float* __restrict__ y) {
    int g = blockIdx.x, t = threadIdx.x; // 128 threads
    __shared__ float m[64];
    __shared__ float h[128];
    __shared__ float rbuf[128];
    if (t < 64) m[t] = mols[g * 64 + t];
    __syncthreads();
    float a = fc1b[t];
#pragma unroll 4
    for (int k = 0; k < 64; k++) a += m[k] * fc1W[k * 128 + t];
    h[t] = softplus_ref(a);
    __syncthreads();
    for (int i = 0; i < 3; i++) {
        float b = fcsb[i * 128 + t];
#pragma unroll 4
        for (int k = 0; k < 128; k++) b += h[k] * fcsW[((size_t)i * 128 + k) * 128 + t];
        __syncthreads();
        h[t] = softplus_ref(b);
        __syncthreads();
    }
    rbuf[t] = h[t] * outW[t];
    __syncthreads();
    if (t < 64) {
        float s2 = rbuf[t] + rbuf[t + 64];
#pragma unroll
        for (int off = 32; off; off >>= 1) s2 += __shfl_xor(s2, off, 64);
        if (t == 0) y[g] = s2 + outb[0];
    }
}

extern "C" void kernel_launch(void* const* d_in, const int* in_sizes, int n_in,
                              void* d_out, int out_size, void* d_ws, size_t ws_size,
                              hipStream_t stream) {
    const int*   an    = (const int*)d_in[0];
    const int*   nbr   = (const int*)d_in[1];
    const float* dist  = (const float*)d_in[2];
    const int*   batch = (const int*)d_in[3];
    const float* emb   = (const float*)d_in[4];
    const float* nucW  = (const float*)d_in[5];
    const float* nucB  = (const float*)d_in[6];
    const float* convW = (const float*)d_in[7];
    const float* convB = (const float*)d_in[8];
    const float* bng   = (const float*)d_in[9];
    const float* bnb   = (const float*)d_in[10];
    const float* lng   = (const float*)d_in[11];
    const float* lnb   = (const float*)d_in[12];
    const float* fc1W  = (const float*)d_in[13];
    const float* fc1b  = (const float*)d_in[14];
    const float* fcsW  = (const float*)d_in[15];
    const float* fcsb  = (const float*)d_in[16];
    const float* outW  = (const float*)d_in[17];
    const float* outb  = (const float*)d_in[18];
    const int* srcI = nbr;
    const int* dstI = nbr + EE;

    char* base = (char*)d_ws;
    size_t off = 0;
    auto alloc = [&](size_t b) { size_t r = off; off += (b + 255) & ~(size_t)255; return r; };
    float*    gtab   = (float*)(base + alloc((size_t)TS * 100 * 4));
    __half2*  Tall   = (__half2*)(base + alloc((size_t)6 * TS * 64 * 4));
    uint4*    Tq4    = (uint4*)(base + alloc((size_t)6 * TS * 32 * 16));
    float4*   Wp     = (float4*)(base + alloc((size_t)6 * 64 * 64 * 16));
    float*    x0     = (float*)(base + alloc((size_t)NN * 64 * 4));
    float*    x1     = (float*)(base + alloc((size_t)NN * 64 * 4));
    uint2*    up4    = (uint2*)(base + alloc((size_t)NN * 32 * 8));
    uint2*    vp4    = (uint2*)(base + alloc((size_t)NN * 32 * 8));
    float*    sums6  = (float*)(base + alloc((size_t)6 * 256 * 4));
    int*      counts = (int*)(base + alloc((size_t)NN * 4));
    int*      cursor = (int*)(base + alloc((size_t)NN * 4));
    int*      rp     = (int*)(base + alloc((size_t)(NN + 1) * 4));
    int*      perm   = (int*)(base + alloc((size_t)EE * 4));
    unsigned* ej     = (unsigned*)(base + alloc((size_t)EE * 4));
    float*    mols   = (float*)(base + alloc((size_t)GG * 64 * 4));
    int*      gp     = (int*)(base + alloc((size_t)(GG + 1) * 4));

    hipMemsetAsync(counts, 0, (size_t)NN * 4, stream);
    hipMemsetAsync(cursor, 0, (size_t)NN * 4, stream);
    hipMemsetAsync(sums6, 0, (size_t)6 * 256 * 4, stream);

    k_gtab<<<(TS * 100 + 255) / 256, 256, 0, stream>>>(gtab);
    k_build_T<<<dim3(TS, 6), 64, 0, stream>>>(gtab, convW, convB, Tall);
    k_build_Tq4<<<dim3(TS / 8, 6), 256, 0, stream>>>(Tall, Tq4);
    k_prepW<<<dim3(64, 6), 64, 0, stream>>>(convW, Wp);
    k_embed<<<(NN + 3) / 4, 256, 0, stream>>>(an, emb, nucW, nucB, x0);
    k_hist<<<(EE + 255) / 256, 256, 0, stream>>>(dstI, counts);
    k_scan<<<1, 1024, 0, stream>>>(counts, rp);
    k_scatter<<<(EE + 255) / 256, 256, 0, stream>>>(dstI, rp, cursor, perm);
    k_edges<<<(EE + 255) / 256, 256, 0, stream>>>(perm, srcI, dist, ej);
    k_gp<<<1, 128, 0, stream>>>(batch, gp);

    float* xin = x0;
    float* xout = x1;
    for (int l = 0; l < 6; l++) {
        k_uv<<<NN / 16, 256, 0, stream>>>(xin, Wp + (size_t)l * 64 * 64, up4, vp4);
        const uint4* Tql = Tq4 + (size_t)l * TS * 32;
        float* sums = sums6 + (size_t)l * 256;
        k_stats<<<2048, 256, 0, stream>>>(up4, vp4, Tql, ej, rp, sums);
        k_agg<<<NN / 4, 256, 0, stream>>>(up4, vp4, Tql, ej, rp, sums,
                                          bng, bnb, lng, lnb, l, xin, xout);
        float* tmp = xin; xin = xout; xout = tmp;
    }
    k_pool2<<<GG, 256, 0, stream>>>(xin, gp, mols);
    k_mlp<<<GG, 128, 0, stream>>>(mols, fc1W, fc1b, fcsW, fcsb, outW, outb, (float*)d_out);
}

// Round 7
// 1194.901 us; speedup vs baseline: 1.0291x; 1.0291x over previous
//
#include <hip/hip_runtime.h>
#include <hip/hip_fp16.h>
#include <cmath>

#define NN 20000
#define EE 500000
#define GG 64
#define TS 2048
#define EPS 1e-5f

__device__ __forceinline__ float softplus_ref(float x) {
    return fmaxf(x, 0.f) + log1pf(__expf(-fabsf(x)));
}
__device__ __forceinline__ float softplus_fast(float x) {
    return fmaxf(x, 0.f) + __logf(1.0f + __expf(-fabsf(x)));
}
__device__ __forceinline__ float sigmoid_fast(float x) {
    return __builtin_amdgcn_rcpf(1.0f + __expf(-x));
}

// gaussian table: g[s][k] = exp(coeff*(d_s - o_k)^2)
__global__ void k_gtab(float* __restrict__ g) {
    int i = blockIdx.x * 256 + threadIdx.x;
    if (i >= TS * 100) return;
    int s = i / 100, k = i - 100 * s;
    float d = s * (6.0f / (TS - 1.0f));
    float o = k * (6.0f / 99.0f);
    float step = 6.0f / 99.0f;
    float coeff = -0.5f / (step * step);
    float df = d - o;
    g[i] = __expf(coeff * df * df);
}

// Paired channel layout: Tp[l][s][t] = half2(T[c=t], T[c=t+64]), t in [0,64)
__global__ void k_build_T(const float* __restrict__ g, const float* __restrict__ convW,
                          const float* __restrict__ convB, __half2* __restrict__ Tp) {
    int t = threadIdx.x;            // 64
    int s = blockIdx.x;             // TS
    int l = blockIdx.y;             // 6
    const float* gr = g + (size_t)s * 100;
    const float* w = convW + ((size_t)l * 228 + 128) * 128;
    float a0 = convB[l * 128 + t];
    float a1 = convB[l * 128 + t + 64];
#pragma unroll 4
    for (int k = 0; k < 100; k++) {
        float gv = gr[k];
        a0 += gv * w[k * 128 + t];
        a1 += gv * w[k * 128 + t + 64];
    }
    Tp[((size_t)l * TS + s) * 64 + t] = __floats2half2_rn(a0, a1);
}

// Row-pair layout: Tq[l][j][t] = uint2( Tp[l][j][t], Tp[l][j+1][t] )
__global__ void k_build_Tq(const __half2* __restrict__ Tp, uint2* __restrict__ Tq) {
    int t = threadIdx.x;            // 64
    int j = blockIdx.x;             // TS
    int l = blockIdx.y;             // 6
    int j1 = min(j + 1, TS - 1);
    unsigned lo = *(const unsigned*)&Tp[((size_t)l * TS + j) * 64 + t];
    unsigned hi = *(const unsigned*)&Tp[((size_t)l * TS + j1) * 64 + t];
    Tq[((size_t)l * TS + j) * 64 + t] = make_uint2(lo, hi);
}

// Wp[l][k][lane] = (W1[k,lane], W1[k,lane+64], W2[k,lane], W2[k,lane+64])
__global__ void k_prepW(const float* __restrict__ convW, float4* __restrict__ Wp) {
    int lane = threadIdx.x;  // 64
    int k = blockIdx.x;      // 64
    int l = blockIdx.y;      // 6
    const float* W1 = convW + ((size_t)l * 228 + k) * 128;
    const float* W2 = convW + ((size_t)l * 228 + 64 + k) * 128;
    Wp[((size_t)l * 64 + k) * 64 + lane] =
        make_float4(W1[lane], W1[lane + 64], W2[lane], W2[lane + 64]);
}

__global__ void k_embed(const int* __restrict__ an, const float* __restrict__ emb,
                        const float* __restrict__ W, const float* __restrict__ b,
                        float* __restrict__ x) {
    int c = threadIdx.x & 63, nl = threadIdx.x >> 6;
    int n = blockIdx.x * 4 + nl;
    if (n >= NN) return;
    const float* e = emb + (size_t)an[n] * 92;
    float acc = b[c];
#pragma unroll 4
    for (int k = 0; k < 92; k++) acc += e[k] * W[k * 64 + c];
    x[(size_t)n * 64 + c] = acc;
}

__global__ void k_hist(const int* __restrict__ dst, int* __restrict__ counts) {
    int e = blockIdx.x * 256 + threadIdx.x;
    if (e < EE) atomicAdd(&counts[dst[e]], 1);
}

__global__ void k_scan(const int* __restrict__ counts, int* __restrict__ rp) {
    __shared__ int buf[1024];
    __shared__ int carry;
    int tid = threadIdx.x;
    if (tid == 0) { carry = 0; rp[0] = 0; }
    __syncthreads();
    for (int base = 0; base < NN; base += 1024) {
        int i = base + tid;
        int val = (i < NN) ? counts[i] : 0;
        buf[tid] = val;
        __syncthreads();
        for (int off = 1; off < 1024; off <<= 1) {
            int t = (tid >= off) ? buf[tid - off] : 0;
            __syncthreads();
            buf[tid] += t;
            __syncthreads();
        }
        if (i < NN) rp[i + 1] = carry + buf[tid];
        __syncthreads();
        if (tid == 0) carry += buf[1023];
        __syncthreads();
    }
}

__global__ void k_scatter(const int* __restrict__ dst, const int* __restrict__ rp,
                          int* __restrict__ cursor, int* __restrict__ perm) {
    int e = blockIdx.x * 256 + threadIdx.x;
    if (e < EE) {
        int d = dst[e];
        int p = atomicAdd(&cursor[d], 1);
        perm[rp[d] + p] = e;
    }
}

// packed edge record in perm order: (src<<17) | (j<<5) | f5 ; plus dstP (uniform stream)
__global__ void k_edges(const int* __restrict__ perm, const int* __restrict__ src,
                        const int* __restrict__ dst, const float* __restrict__ dist,
                        unsigned* __restrict__ ej, unsigned* __restrict__ dstP) {
    int idx = blockIdx.x * 256 + threadIdx.x;
    if (idx >= EE) return;
    int e = perm[idx];
    float t = dist[e] * ((TS - 1.0f) / 6.0f);
    int j = (int)t;
    if (j > TS - 2) j = TS - 2;
    float f = t - (float)j;
    f = fminf(fmaxf(f, 0.0f), 1.0f);
    unsigned f5 = (unsigned)(f * 32.0f);
    if (f5 > 31u) f5 = 31u;
    ej[idx] = ((unsigned)src[e] << 17) | ((unsigned)j << 5) | f5;
    dstP[idx] = (unsigned)dst[e];
}

// u,v: 4 nodes per wave, Wp float4 loads, readlane broadcast (round-5 layout)
__global__ void __launch_bounds__(256) k_uv(const float* __restrict__ x,
                                            const float4* __restrict__ Wp,
                                            __half2* __restrict__ up, __half2* __restrict__ vp) {
    int lane = threadIdx.x & 63;
    int wv = __builtin_amdgcn_readfirstlane(threadIdx.x >> 6);
    int n0 = (blockIdx.x * 4 + wv) * 4;
    float xa = x[(size_t)(n0 + 0) * 64 + lane];
    float xb = x[(size_t)(n0 + 1) * 64 + lane];
    float xc = x[(size_t)(n0 + 2) * 64 + lane];
    float xd = x[(size_t)(n0 + 3) * 64 + lane];
    float2 ua = {0, 0}, ub = {0, 0}, uc = {0, 0}, ud = {0, 0};
    float2 va = {0, 0}, vb = {0, 0}, vc = {0, 0}, vd = {0, 0};
#pragma unroll 8
    for (int k = 0; k < 64; k++) {
        float4 w = Wp[k * 64 + lane];
        float ka = __uint_as_float(__builtin_amdgcn_readlane(__float_as_uint(xa), k));
        float kb = __uint_as_float(__builtin_amdgcn_readlane(__float_as_uint(xb), k));
        float kc = __uint_as_float(__builtin_amdgcn_readlane(__float_as_uint(xc), k));
        float kd = __uint_as_float(__builtin_amdgcn_readlane(__float_as_uint(xd), k));
        ua.x += ka * w.x; ua.y += ka * w.y; va.x += ka * w.z; va.y += ka * w.w;
        ub.x += kb * w.x; ub.y += kb * w.y; vb.x += kb * w.z; vb.y += kb * w.w;
        uc.x += kc * w.x; uc.y += kc * w.y; vc.x += kc * w.z; vc.y += kc * w.w;
        ud.x += kd * w.x; ud.y += kd * w.y; vd.x += kd * w.z; vd.y += kd * w.w;
    }
    up[(size_t)(n0 + 0) * 64 + lane] = __floats2half2_rn(ua.x, ua.y);
    up[(size_t)(n0 + 1) * 64 + lane] = __floats2half2_rn(ub.x, ub.y);
    up[(size_t)(n0 + 2) * 64 + lane] = __floats2half2_rn(uc.x, uc.y);
    up[(size_t)(n0 + 3) * 64 + lane] = __floats2half2_rn(ud.x, ud.y);
    vp[(size_t)(n0 + 0) * 64 + lane] = __floats2half2_rn(va.x, va.y);
    vp[(size_t)(n0 + 1) * 64 + lane] = __floats2half2_rn(vb.x, vb.y);
    vp[(size_t)(n0 + 2) * 64 + lane] = __floats2half2_rn(vc.x, vc.y);
    vp[(size_t)(n0 + 3) * 64 + lane] = __floats2half2_rn(vd.x, vd.y);
}

#define STATS_BLOCKS 2048
#define CHUNK 62   // ceil(EE / (STATS_BLOCKS*4))

// pass A: BN stats; EDGE-PARALLEL. Each wave owns a contiguous 62-edge chunk of
// the dst-sorted stream: perfect balance, uniform scalar ej/dst loads, u L1-hot.
__global__ void __launch_bounds__(256) k_stats(
    const __half2* __restrict__ up, const __half2* __restrict__ vp,
    const uint2* __restrict__ Tq, const unsigned* __restrict__ ej,
    const unsigned* __restrict__ dstP, float* __restrict__ sums) {
    int lane = threadIdx.x & 63;
    int wv = threadIdx.x >> 6;
    int w = blockIdx.x * 4 + wv;
    int rs = w * CHUNK;
    int re = min(rs + CHUNK, EE);
    float sx = 0.f, sy = 0.f, qx = 0.f, qy = 0.f;
    int idx = rs;
    for (; idx + 16 <= re; idx += 16) {
        unsigned e[16], d[16];
#pragma unroll
        for (int t = 0; t < 16; t++) { e[t] = ej[idx + t]; d[t] = dstP[idx + t]; }
        __half2 uh[16], vh[16]; uint2 th[16];
#pragma unroll
        for (int t = 0; t < 16; t++) {
            uh[t] = up[(size_t)d[t] * 64 + lane];
            vh[t] = vp[(size_t)(e[t] >> 17) * 64 + lane];
            th[t] = Tq[(size_t)((e[t] >> 5) & 0xFFFu) * 64 + lane];
        }
#pragma unroll
        for (int t = 0; t < 16; t++) {
            float f = ((float)(e[t] & 31u) + 0.5f) * (1.0f / 32.0f);
            float2 uu = __half22float2(uh[t]);
            float2 vv = __half22float2(vh[t]);
            float2 t0 = __half22float2(*(const __half2*)&th[t].x);
            float2 t1 = __half22float2(*(const __half2*)&th[t].y);
            float z0 = uu.x + vv.x + t0.x + (t1.x - t0.x) * f;
            float z1 = uu.y + vv.y + t0.y + (t1.y - t0.y) * f;
            sx += z0; qx += z0 * z0;
            sy += z1; qy += z1 * z1;
        }
    }
    for (; idx < re; ++idx) {
        unsigned e = ej[idx], d = dstP[idx];
        float f = ((float)(e & 31u) + 0.5f) * (1.0f / 32.0f);
        float2 uu = __half22float2(up[(size_t)d * 64 + lane]);
        float2 vv = __half22float2(vp[(size_t)(e >> 17) * 64 + lane]);
        uint2 tq = Tq[(size_t)((e >> 5) & 0xFFFu) * 64 + lane];
        float2 t0 = __half22float2(*(const __half2*)&tq.x);
        float2 t1 = __half22float2(*(const __half2*)&tq.y);
        float z0 = uu.x + vv.x + t0.x + (t1.x - t0.x) * f;
        float z1 = uu.y + vv.y + t0.y + (t1.y - t0.y) * f;
        sx += z0; qx += z0 * z0;
        sy += z1; qy += z1 * z1;
    }
    __shared__ float red[4][64][4];
    red[wv][lane][0] = sx; red[wv][lane][1] = sy;
    red[wv][lane][2] = qx; red[wv][lane][3] = qy;
    __syncthreads();
    if (wv == 0) {
        for (int r = 1; r < 4; r++) {
            sx += red[r][lane][0]; sy += red[r][lane][1];
            qx += red[r][lane][2]; qy += red[r][lane][3];
        }
        atomicAdd(&sums[lane], sx);
        atomicAdd(&sums[lane + 64], sy);
        atomicAdd(&sums[128 + lane], qx);
        atomicAdd(&sums[192 + lane], qy);
    }
}

// pass B: wave-per-node; inline BN finalize; 8-deep pipeline; LN epilogue in shuffles
__global__ void __launch_bounds__(256) k_agg(
    const __half2* __restrict__ up, const __half2* __restrict__ vp,
    const uint2* __restrict__ Tq, const unsigned* __restrict__ ej,
    const int* __restrict__ rp, const float* __restrict__ sums,
    const float* __restrict__ bng, const float* __restrict__ bnb,
    const float* __restrict__ lng, const float* __restrict__ lnb,
    int l, const float* __restrict__ xin, float* __restrict__ xout) {
    int lane = threadIdx.x & 63;
    int wv = __builtin_amdgcn_readfirstlane(threadIdx.x >> 6);
    int i = blockIdx.x * 4 + wv;
    float mu1 = sums[lane] * (1.0f / EE);
    float var1 = sums[128 + lane] * (1.0f / EE) - mu1 * mu1;
    float A1 = rsqrtf(var1 + EPS) * bng[l * 128 + lane];
    float B1 = bnb[l * 128 + lane] - mu1 * A1;
    float mu2 = sums[64 + lane] * (1.0f / EE);
    float var2 = sums[192 + lane] * (1.0f / EE) - mu2 * mu2;
    float A2 = rsqrtf(var2 + EPS) * bng[l * 128 + 64 + lane];
    float B2 = bnb[l * 128 + 64 + lane] - mu2 * A2;

    float2 uu = __half22float2(up[(size_t)i * 64 + lane]);
    float xr = xin[(size_t)i * 64 + lane];
    float acc = 0.f;
    int rs = __builtin_amdgcn_readfirstlane(rp[i]);
    int re = __builtin_amdgcn_readfirstlane(rp[i + 1]);
    int idx = rs;
    for (; idx + 8 <= re; idx += 8) {
        unsigned e[8];
#pragma unroll
        for (int t = 0; t < 8; t++) e[t] = ej[idx + t];
        __half2 vh[8]; uint2 th[8];
#pragma unroll
        for (int t = 0; t < 8; t++) {
            vh[t] = vp[(size_t)(e[t] >> 17) * 64 + lane];
            th[t] = Tq[(size_t)((e[t] >> 5) & 0xFFFu) * 64 + lane];
        }
#pragma unroll
        for (int t = 0; t < 8; t++) {
            float f = ((float)(e[t] & 31u) + 0.5f) * (1.0f / 32.0f);
            float2 vv = __half22float2(vh[t]);
            float2 t0 = __half22float2(*(const __half2*)&th[t].x);
            float2 t1 = __half22float2(*(const __half2*)&th[t].y);
            float z0 = (uu.x + vv.x + t0.x + (t1.x - t0.x) * f) * A1 + B1;
            float z1 = (uu.y + vv.y + t0.y + (t1.y - t0.y) * f) * A2 + B2;
            acc += sigmoid_fast(z0) * softplus_fast(z1);
        }
    }
    for (; idx < re; ++idx) {
        unsigned e = ej[idx];
        float f = ((float)(e & 31u) + 0.5f) * (1.0f / 32.0f);
        float2 vv = __half22float2(vp[(size_t)(e >> 17) * 64 + lane]);
        uint2 tq = Tq[(size_t)((e >> 5) & 0xFFFu) * 64 + lane];
        float2 t0 = __half22float2(*(const __half2*)&tq.x);
        float2 t1 = __half22float2(*(const __half2*)&tq.y);
        float z0 = (uu.x + vv.x + t0.x + (t1.x - t0.x) * f) * A1 + B1;
        float z1 = (uu.y + vv.y + t0.y + (t1.y - t0.y) * f) * A2 + B2;
        acc += sigmoid_fast(z0) * softplus_fast(z1);
    }
    float s = acc;
#pragma unroll
    for (int off = 32; off; off >>= 1) s += __shfl_xor(s, off, 64);
    float mean = s * (1.0f / 64.0f);
    float e0v = acc - mean;
    float vv2 = e0v * e0v;
#pragma unroll
    for (int off = 32; off; off >>= 1) vv2 += __shfl_xor(vv2, off, 64);
    float var = vv2 * (1.0f / 64.0f);
    float h = e0v * rsqrtf(var + EPS) * lng[l * 64 + lane] + lnb[l * 64 + lane];
    xout[(size_t)i * 64 + lane] = softplus_ref(h + xr);
}

// batch sorted -> graph row pointers by binary search
__global__ void k_gp(const int* __restrict__ batch, int* __restrict__ gp) {
    int g = threadIdx.x;
    if (g > GG) return;
    int lo = 0, hi = NN;
    while (lo < hi) {
        int mid = (lo + hi) >> 1;
        if (batch[mid] < g) lo = mid + 1; else hi = mid;
    }
    gp[g] = lo;
}

// atomic-free segmented mean-pool
__global__ void k_pool2(const float* __restrict__ x, const int* __restrict__ gp,
                        float* __restrict__ mols) {
    int g = blockIdx.x;
    int lane = threadIdx.x & 63, slot = threadIdx.x >> 6;
    int s0 = gp[g], s1 = gp[g + 1];
    float acc = 0.f;
    for (int n = s0 + slot; n < s1; n += 4) acc += x[(size_t)n * 64 + lane];
    __shared__ float red[4][64];
    red[slot][lane] = acc;
    __syncthreads();
    if (slot == 0) {
        float a = red[0][lane] + red[1][lane] + red[2][lane] + red[3][lane];
        float cc = fmaxf((float)(s1 - s0), 1.0f);
        mols[g * 64 + lane] = a / cc;
    }
}

__global__ void k_mlp(const float* __restrict__ mols,
                      const float* __restrict__ fc1W, const float* __restrict__ fc1b,
                      const float* __restrict__ fcsW, const float* __restrict__ fcsb,
                      const float* __restrict__ outW, const float* __restrict__ outb,
                      float* __restrict__ y) {
    int g = blockIdx.x, t = threadIdx.x; // 128 threads
    __shared__ float m[64];
    __shared__ float h[128];
    __shared__ float rbuf[128];
    if (t < 64) m[t] = mols[g * 64 + t];
    __syncthreads();
    float a = fc1b[t];
#pragma unroll 4
    for (int k = 0; k < 64; k++) a += m[k] * fc1W[k * 128 + t];
    h[t] = softplus_ref(a);
    __syncthreads();
    for (int i = 0; i < 3; i++) {
        float b = fcsb[i * 128 + t];
#pragma unroll 4
        for (int k = 0; k < 128; k++) b += h[k] * fcsW[((size_t)i * 128 + k) * 128 + t];
        __syncthreads();
        h[t] = softplus_ref(b);
        __syncthreads();
    }
    rbuf[t] = h[t] * outW[t];
    __syncthreads();
    if (t < 64) {
        float s2 = rbuf[t] + rbuf[t + 64];
#pragma unroll
        for (int off = 32; off; off >>= 1) s2 += __shfl_xor(s2, off, 64);
        if (t == 0) y[g] = s2 + outb[0];
    }
}

extern "C" void kernel_launch(void* const* d_in, const int* in_sizes, int n_in,
                              void* d_out, int out_size, void* d_ws, size_t ws_size,
                              hipStream_t stream) {
    const int*   an    = (const int*)d_in[0];
    const int*   nbr   = (const int*)d_in[1];
    const float* dist  = (const float*)d_in[2];
    const int*   batch = (const int*)d_in[3];
    const float* emb   = (const float*)d_in[4];
    const float* nucW  = (const float*)d_in[5];
    const float* nucB  = (const float*)d_in[6];
    const float* convW = (const float*)d_in[7];
    const float* convB = (const float*)d_in[8];
    const float* bng   = (const float*)d_in[9];
    const float* bnb   = (const float*)d_in[10];
    const float* lng   = (const float*)d_in[11];
    const float* lnb   = (const float*)d_in[12];
    const float* fc1W  = (const float*)d_in[13];
    const float* fc1b  = (const float*)d_in[14];
    const float* fcsW  = (const float*)d_in[15];
    const float* fcsb  = (const float*)d_in[16];
    const float* outW  = (const float*)d_in[17];
    const float* outb  = (const float*)d_in[18];
    const int* srcI = nbr;
    const int* dstI = nbr + EE;

    char* base = (char*)d_ws;
    size_t off = 0;
    auto alloc = [&](size_t b) { size_t r = off; off += (b + 255) & ~(size_t)255; return r; };
    float*    gtab   = (float*)(base + alloc((size_t)TS * 100 * 4));
    __half2*  Tall   = (__half2*)(base + alloc((size_t)6 * TS * 64 * 4));
    uint2*    Tq     = (uint2*)(base + alloc((size_t)6 * TS * 64 * 8));
    float4*   Wp     = (float4*)(base + alloc((size_t)6 * 64 * 64 * 16));
    float*    x0     = (float*)(base + alloc((size_t)NN * 64 * 4));
    float*    x1     = (float*)(base + alloc((size_t)NN * 64 * 4));
    __half2*  up     = (__half2*)(base + alloc((size_t)NN * 64 * 4));
    __half2*  vp     = (__half2*)(base + alloc((size_t)NN * 64 * 4));
    float*    sums6  = (float*)(base + alloc((size_t)6 * 256 * 4));
    int*      counts = (int*)(base + alloc((size_t)NN * 4));
    int*      cursor = (int*)(base + alloc((size_t)NN * 4));
    int*      rp     = (int*)(base + alloc((size_t)(NN + 1) * 4));
    int*      perm   = (int*)(base + alloc((size_t)EE * 4));
    unsigned* ej     = (unsigned*)(base + alloc((size_t)EE * 4));
    unsigned* dstP   = (unsigned*)(base + alloc((size_t)EE * 4));
    float*    mols   = (float*)(base + alloc((size_t)GG * 64 * 4));
    int*      gp     = (int*)(base + alloc((size_t)(GG + 1) * 4));

    hipMemsetAsync(counts, 0, (size_t)NN * 4, stream);
    hipMemsetAsync(cursor, 0, (size_t)NN * 4, stream);
    hipMemsetAsync(sums6, 0, (size_t)6 * 256 * 4, stream);

    k_gtab<<<(TS * 100 + 255) / 256, 256, 0, stream>>>(gtab);
    k_build_T<<<dim3(TS, 6), 64, 0, stream>>>(gtab, convW, convB, Tall);
    k_build_Tq<<<dim3(TS, 6), 64, 0, stream>>>(Tall, Tq);
    k_prepW<<<dim3(64, 6), 64, 0, stream>>>(convW, Wp);
    k_embed<<<(NN + 3) / 4, 256, 0, stream>>>(an, emb, nucW, nucB, x0);
    k_hist<<<(EE + 255) / 256, 256, 0, stream>>>(dstI, counts);
    k_scan<<<1, 1024, 0, stream>>>(counts, rp);
    k_scatter<<<(EE + 255) / 256, 256, 0, stream>>>(dstI, rp, cursor, perm);
    k_edges<<<(EE + 255) / 256, 256, 0, stream>>>(perm, srcI, dstI, dist, ej, dstP);
    k_gp<<<1, 128, 0, stream>>>(batch, gp);

    float* xin = x0;
    float* xout = x1;
    for (int l = 0; l < 6; l++) {
        k_uv<<<NN / 16, 256, 0, stream>>>(xin, Wp + (size_t)l * 64 * 64, up, vp);
        const uint2* Tql = Tq + (size_t)l * TS * 64;
        float* sums = sums6 + (size_t)l * 256;
        k_stats<<<STATS_BLOCKS, 256, 0, stream>>>(up, vp, Tql, ej, dstP, sums);
        k_agg<<<NN / 4, 256, 0, stream>>>(up, vp, Tql, ej, rp, sums,
                                          bng, bnb, lng, lnb, l, xin, xout);
        float* tmp = xin; xin = xout; xout = tmp;
    }
    k_pool2<<<GG, 256, 0, stream>>>(xin, gp, mols);
    k_mlp<<<GG, 128, 0, stream>>>(mols, fc1W, fc1b, fcsW, fcsb, outW, outb, (float*)d_out);
}